// Round 19
// baseline (155.292 us; speedup 1.0000x reference)
//
#include <hip/hip_runtime.h>

typedef __bf16 bf16_t;
typedef __bf16 bf16x4 __attribute__((ext_vector_type(4)));
typedef __bf16 bf16x8 __attribute__((ext_vector_type(8)));
typedef float  f32x4  __attribute__((ext_vector_type(4)));

#define HEADS 8
#define HEAD_DIM 32
#define DIM 256
#define BL 10
#define SEQ 1024
#define M_TOTAL (BL*SEQ)
#define QK_SCALE 0.17677669529663687f   // 1/sqrt(32)
#define LOG2E 1.4426950408889634f
#define SQRT_LOG2E 1.2011224087864498f
#define NPOS (63*63)

#define NCASTW 36                        // Ws1^T (8192) + bias_all (832)
#define NTRANS 96
#define NPREP (NCASTW + NTRANS + 16)

__device__ __forceinline__ int swz_idx(int row, int col) {
  return row*64 + (col ^ ((row & 7) << 3));
}
__device__ __forceinline__ int swz256(int row, int col) {
  return row*256 + (col ^ ((row & 7) << 3));
}

// ---------------- prep: Ws1^T + bias | weight transposes | pos table ----------------
__global__ __launch_bounds__(256) void prep_all_kernel(
    const float* __restrict__ Ws1,
    const float* __restrict__ bq, const float* __restrict__ bk,
    const float* __restrict__ bv, const float* __restrict__ bs1,
    const float* __restrict__ Wq, const float* __restrict__ Wk, const float* __restrict__ Wv,
    const float* __restrict__ Wo, const float* __restrict__ Wg,
    const float* __restrict__ Wp1, const float* __restrict__ bp1,
    const float* __restrict__ Wp2, const float* __restrict__ bp2,
    bf16_t* __restrict__ btall, float* __restrict__ bias_all,
    bf16_t* __restrict__ wot, bf16_t* __restrict__ wg1t, bf16_t* __restrict__ wg2t,
    float* __restrict__ posT)
{
  __shared__ float tile[64][65];
  const int bid = blockIdx.x;
  const int tid = threadIdx.x;

  if (bid < NCASTW) {
    const int i = bid*256 + tid;
    if (i < 8192) {
      const int m = i >> 8, k = i & 255;
      btall[(768 + m)*256 + k] = (bf16_t)Ws1[k*32 + m];
      return;
    }
    const int idx = i - 8192;
    if (idx < 832) {
      bias_all[idx] = (idx < 256) ? bq[idx] : (idx < 512) ? bk[idx-256] :
                      (idx < 768) ? bv[idx-512] : (idx < 800) ? bs1[idx-768] : 0.f;
    }
    return;
  }

  if (bid < NCASTW + NTRANS) {
    const int t0 = bid - NCASTW;
    const int z = t0 >> 4, bi = (t0 & 15) >> 2, bj = t0 & 3;
    const float* src; bf16_t* dst;
    switch (z) {
      case 0: src = Wq;          dst = btall;          break;
      case 1: src = Wk;          dst = btall + 65536;  break;
      case 2: src = Wv;          dst = btall + 131072; break;
      case 3: src = Wo;          dst = wot;            break;
      case 4: src = Wg;          dst = wg1t;           break;
      default: src = Wg + 65536; dst = wg2t;           break;
    }
    const int tr = tid >> 4, tc = tid & 15;
    #pragma unroll
    for (int i = 0; i < 4; ++i) {
      const float4 v = *(const float4*)(src + (size_t)(bi*64 + tr + 16*i)*256 + bj*64 + tc*4);
      float* tp = &tile[tr + 16*i][tc*4];
      tp[0]=v.x; tp[1]=v.y; tp[2]=v.z; tp[3]=v.w;
    }
    __syncthreads();
    #pragma unroll
    for (int i = 0; i < 4; ++i) {
      bf16x4 o;
      #pragma unroll
      for (int e = 0; e < 4; ++e) o[e] = (bf16_t)tile[tc*4 + e][tr + 16*i];
      *(bf16x4*)(dst + (size_t)(bj*64 + tr + 16*i)*256 + bi*64 + tc*4) = o;
    }
    return;
  }

  // ---- pos table (x LOG2E) ----
  {
    float* sm = &tile[0][0];
    float* w1 = sm; float* b1 = sm + 96; float* w2 = sm + 128; float* b2 = sm + 384;
    if (tid < 96) w1[tid] = Wp1[tid];
    if (tid < 32) b1[tid] = bp1[tid];
    w2[tid] = Wp2[tid];
    if (tid < 8)  b2[tid] = bp2[tid];
    __syncthreads();
    const int p = (bid - NCASTW - NTRANS)*256 + tid;
    if (p >= NPOS) return;
    const float dy = (float)(p / 63 - 31);
    const float dx = (float)(p % 63 - 31);
    const float dist = sqrtf(dy*dy + dx*dx);
    float o[8];
    #pragma unroll
    for (int t = 0; t < 8; ++t) o[t] = b2[t];
    #pragma unroll
    for (int m = 0; m < 32; ++m) {
      float hv = fmaf(dy, w1[m], fmaf(dx, w1[32+m], fmaf(dist, w1[64+m], b1[m])));
      hv = fmaxf(hv, 0.f);
      #pragma unroll
      for (int t = 0; t < 8; ++t) o[t] = fmaf(hv, w2[m*8+t], o[t]);
    }
    #pragma unroll
    for (int t = 0; t < 8; ++t) posT[t*NPOS + p] = o[t]*LOG2E;
  }
}

// ---------------- fused QKV + hidden + s projection (XCD-swizzled, x inline-cast) ----------------
__global__ __launch_bounds__(256) void qkv_kernel(
    const float* __restrict__ x, const bf16_t* __restrict__ btall,
    const float* __restrict__ bias_all, const float* __restrict__ Ws2,
    const float* __restrict__ bs2,
    bf16_t* __restrict__ qbuf, bf16_t* __restrict__ kbuf, bf16_t* __restrict__ vbuf,
    bf16_t* __restrict__ sbb)
{
  __shared__ float hidlds[64][33];
  const int wg = blockIdx.x;
  const int xcd = wg & 7, within = wg >> 3;      // within 0..259
  const int mt = xcd*20 + within/13;
  const int ngb = within - (within/13)*13;
  const int tid = threadIdx.x;
  const int w = tid >> 6, lane = tid & 63, g = lane >> 4, l15 = lane & 15;
  const int arow = mt*64 + w*16 + l15;
  const float4* Arow = (const float4*)(x + (size_t)arow*DIM);
  bf16x8 af[8];
  #pragma unroll
  for (int kc = 0; kc < 8; ++kc) {
    const float4 f0 = Arow[kc*8 + g*2], f1 = Arow[kc*8 + g*2 + 1];
    bf16x8 v;
    v[0]=(bf16_t)f0.x; v[1]=(bf16_t)f0.y; v[2]=(bf16_t)f0.z; v[3]=(bf16_t)f0.w;
    v[4]=(bf16_t)f1.x; v[5]=(bf16_t)f1.y; v[6]=(bf16_t)f1.z; v[7]=(bf16_t)f1.w;
    af[kc] = v;
  }
  if (ngb < 12) {
    bf16_t* dst = (ngb < 4) ? qbuf : (ngb < 8) ? kbuf : vbuf;
    const int coloff = (ngb & 3) * 64;
    const float scale = (ngb < 4) ? QK_SCALE*LOG2E : 1.f;
    #pragma unroll
    for (int c = 0; c < 4; ++c) {
      const int n = ngb*64 + c*16 + l15;
      const bf16x8* Brow = (const bf16x8*)(btall + (size_t)n*DIM);
      f32x4 acc = {0.f,0.f,0.f,0.f};
      #pragma unroll
      for (int kc = 0; kc < 8; ++kc)
        acc = __builtin_amdgcn_mfma_f32_16x16x32_bf16(af[kc], Brow[kc*4+g], acc, 0, 0, 0);
      const float bvv = bias_all[n];
      #pragma unroll
      for (int r = 0; r < 4; ++r) {
        const int row = mt*64 + w*16 + g*4 + r;
        dst[(size_t)row*DIM + coloff + c*16 + l15] = (bf16_t)((acc[r] + bvv)*scale);
      }
    }
  } else {
    #pragma unroll
    for (int c = 0; c < 2; ++c) {
      const int n = 768 + c*16 + l15;
      const bf16x8* Brow = (const bf16x8*)(btall + (size_t)n*DIM);
      f32x4 acc = {0.f,0.f,0.f,0.f};
      #pragma unroll
      for (int kc = 0; kc < 8; ++kc)
        acc = __builtin_amdgcn_mfma_f32_16x16x32_bf16(af[kc], Brow[kc*4+g], acc, 0, 0, 0);
      const float bvv = bias_all[n];
      #pragma unroll
      for (int r = 0; r < 4; ++r)
        hidlds[w*16 + g*4 + r][c*16 + l15] = fmaxf(acc[r] + bvv, 0.f);
    }
    __syncthreads();
    if (tid < 64) {
      float sv[8];
      #pragma unroll
      for (int t = 0; t < 8; ++t) sv[t] = bs2[t];
      #pragma unroll
      for (int m = 0; m < 32; ++m) {
        const float hv = hidlds[tid][m];
        #pragma unroll
        for (int t = 0; t < 8; ++t) sv[t] = fmaf(hv, Ws2[m*8+t], sv[t]);
      }
      bf16x8 o;
      #pragma unroll
      for (int t = 0; t < 8; ++t) o[t] = (bf16_t)(sv[t]*SQRT_LOG2E);
      *(bf16x8*)(sbb + (size_t)(mt*64 + tid)*8) = o;
    }
  }
}

// ---------------- flash attention (r14 body): swapped QK^T, dbuf K/V, ----
// ---------------- lane-local softmax + in-register row-sum ----------------
__global__ __launch_bounds__(256) void attn_kernel(
    const bf16_t* __restrict__ qb, const bf16_t* __restrict__ kb,
    const bf16_t* __restrict__ vb, const bf16_t* __restrict__ sbb,
    const float* __restrict__ posT, bf16_t* __restrict__ att)
{
  __shared__ __align__(16) bf16_t lk[2][64*64];   // cols 0-31 K, 32-39 s, 40-63 zero
  __shared__ __align__(16) bf16_t lv[2][32*64];   // rows 0-31 V^T
  __shared__ __align__(16) bf16_t lp[64*64];      // P[q][j], wave-local rows
  __shared__ float ptab[33*63];

  const int wg = blockIdx.x;
  const int xcd = wg & 7, within = wg >> 3;
  const int pair = xcd*10 + (within >> 4);
  const int it = within & 15;
  const int h = pair & 7, b = pair >> 3;
  const int i0 = it*64, iy0 = it*2;
  const int tid = threadIdx.x;
  const int w = tid >> 6, lane = tid & 63, g = lane >> 4, l15 = lane & 15;
  const int r4 = tid >> 2, q4 = tid & 3;

  // ---- stage pos slice ----
  for (int p = tid; p < 33*63; p += 256) {
    const int rr = p / 63, cc = p - rr*63;
    ptab[p] = posT[h*NPOS + (iy0 + rr)*63 + cc];
  }
  // ---- one-time: lk zero cols 40..63 in both buffers ----
  for (int p = tid; p < 384; p += 256) {
    const int bufi = p / 192, rem = p - bufi*192;
    const int rr = rem / 3, ch = 5 + (rem % 3);
    bf16x8 z = {};
    *(bf16x8*)&lk[bufi][swz_idx(rr, ch*8)] = z;
  }

  // ---- Q fragments ----
  const int qrow = b*SEQ + i0 + w*16 + l15;
  const bf16x8 aq0 = *(const bf16x8*)(qb + (size_t)qrow*DIM + h*HEAD_DIM + g*8);
  bf16x8 aq1 = {};
  if (g == 0) aq1 = *(const bf16x8*)(sbb + (size_t)qrow*8);

  const int iq = i0 + w*16 + l15;
  const int rbase_i = (iq >> 5) - iy0 + 31;   // {31,32}
  const int ixr = iq & 31;

  // ---- tile 0 into regs, write buf0 ----
  bf16x8 kreg = *(const bf16x8*)(kb + (size_t)(b*SEQ + r4)*DIM + h*HEAD_DIM + q4*8);
  bf16x8 vreg = *(const bf16x8*)(vb + (size_t)(b*SEQ + r4)*DIM + h*HEAD_DIM + q4*8);
  bf16x8 sreg = {};
  if (tid < 64) sreg = *(const bf16x8*)(sbb + (size_t)(b*SEQ + tid)*8);
  *(bf16x8*)&lk[0][swz_idx(r4, q4*8)] = kreg;
  #pragma unroll
  for (int e = 0; e < 8; ++e) {
    const int d = q4*8 + e;
    lv[0][d*64 + (r4 ^ ((d & 7) << 3))] = vreg[e];
  }
  if (tid < 64) *(bf16x8*)&lk[0][swz_idx(tid, 32)] = sreg;
  __syncthreads();

  f32x4 accO0 = {0.f,0.f,0.f,0.f}, accO1 = {0.f,0.f,0.f,0.f};
  float mrow = -1e30f, lrow = 0.f;

  for (int jt = 0; jt < 16; ++jt) {
    const int pb = jt & 1;
    // ---- prefetch next tile into regs (overlaps with compute) ----
    if (jt < 15) {
      const int grow = b*SEQ + jt*64 + 64;
      kreg = *(const bf16x8*)(kb + (size_t)(grow + r4)*DIM + h*HEAD_DIM + q4*8);
      vreg = *(const bf16x8*)(vb + (size_t)(grow + r4)*DIM + h*HEAD_DIM + q4*8);
      if (tid < 64) sreg = *(const bf16x8*)(sbb + (size_t)(grow + tid)*8);
    }

    // ---- QK^T swapped: K as A, Q as B  ->  D[j][q] ----
    f32x4 s4[4];
    #pragma unroll
    for (int c = 0; c < 4; ++c) {
      const bf16x8 kf0 = *(const bf16x8*)&lk[pb][swz_idx(c*16 + l15, g*8)];
      const bf16x8 kf1 = *(const bf16x8*)&lk[pb][swz_idx(c*16 + l15, 32 + g*8)];
      f32x4 acc = {0.f,0.f,0.f,0.f};
      acc = __builtin_amdgcn_mfma_f32_16x16x32_bf16(kf0, aq0, acc, 0, 0, 0);
      acc = __builtin_amdgcn_mfma_f32_16x16x32_bf16(kf1, aq1, acc, 0, 0, 0);
      s4[c] = acc;
    }

    // ---- + pos (i fixed per thread, j varies) ----
    #pragma unroll
    for (int c = 0; c < 4; ++c) {
      #pragma unroll
      for (int r = 0; r < 4; ++r) {
        const int jl = c*16 + g*4 + r;
        const int jy = jt*2 + (jl >> 5);
        const int jx = jl & 31;
        s4[c][r] += ptab[(rbase_i - jy)*63 + (ixr - jx + 31)];
      }
    }

    // ---- softmax over j for fixed q: lane-local max + 2 shfl ----
    float m16 = s4[0][0];
    #pragma unroll
    for (int c = 0; c < 4; ++c) {
      #pragma unroll
      for (int r = 0; r < 4; ++r) m16 = fmaxf(m16, s4[c][r]);
    }
    m16 = fmaxf(m16, __shfl_xor(m16, 16));
    m16 = fmaxf(m16, __shfl_xor(m16, 32));
    if (__any(m16 > mrow + 8.f)) {
      const float mn = fmaxf(mrow, m16);
      const float alpha = exp2f(mrow - mn);
      mrow = mn;
      lrow *= alpha;
      #pragma unroll
      for (int r = 0; r < 4; ++r) {
        const float aO = __shfl(alpha, g*16 + g*4 + r);   // alpha of q = w*16+g*4+r
        accO0[r] *= aO; accO1[r] *= aO;
      }
    }
    float rsum = 0.f;
    #pragma unroll
    for (int c = 0; c < 4; ++c) {
      #pragma unroll
      for (int r = 0; r < 4; ++r) {
        s4[c][r] = exp2f(s4[c][r] - mrow);
        rsum += s4[c][r];
      }
    }
    lrow += rsum;

    // ---- P -> LDS (wave-local rows, b64 runs) ----
    #pragma unroll
    for (int c = 0; c < 4; ++c) {
      bf16x4 o;
      #pragma unroll
      for (int r = 0; r < 4; ++r) o[r] = (bf16_t)s4[c][r];
      *(bf16x4*)&lp[swz_idx(w*16 + l15, c*16 + g*4)] = o;
    }

    // ---- PV ----
    const int prow = w*16 + l15;
    #pragma unroll
    for (int kc = 0; kc < 2; ++kc) {
      const bf16x8 ap  = *(const bf16x8*)&lp[swz_idx(prow, kc*32 + g*8)];
      const bf16x8 bv0 = *(const bf16x8*)&lv[pb][swz_idx(l15,      kc*32 + g*8)];
      const bf16x8 bv1 = *(const bf16x8*)&lv[pb][swz_idx(16 + l15, kc*32 + g*8)];
      accO0 = __builtin_amdgcn_mfma_f32_16x16x32_bf16(ap, bv0, accO0, 0, 0, 0);
      accO1 = __builtin_amdgcn_mfma_f32_16x16x32_bf16(ap, bv1, accO1, 0, 0, 0);
    }

    // ---- write staged regs -> buf pb^1 ----
    if (jt < 15) {
      *(bf16x8*)&lk[pb^1][swz_idx(r4, q4*8)] = kreg;
      #pragma unroll
      for (int e = 0; e < 8; ++e) {
        const int d = q4*8 + e;
        lv[pb^1][d*64 + (r4 ^ ((d & 7) << 3))] = vreg[e];
      }
      if (tid < 64) *(bf16x8*)&lk[pb^1][swz_idx(tid, 32)] = sreg;
    }
    __syncthreads();
  }

  // ---- epilogue: reduce lrow across g-lanes, broadcast per output row ----
  lrow += __shfl_xor(lrow, 16);
  lrow += __shfl_xor(lrow, 32);
  #pragma unroll
  for (int r = 0; r < 4; ++r) {
    const int row = b*SEQ + i0 + w*16 + g*4 + r;
    const float inv = 1.f / __shfl(lrow, g*16 + g*4 + r);
    att[(size_t)row*DIM + h*HEAD_DIM + l15]      = (bf16_t)(accO0[r]*inv);
    att[(size_t)row*DIM + h*HEAD_DIM + 16 + l15] = (bf16_t)(accO1[r]*inv);
  }
}

// ---------------- fused Wo-projection + gate (XCD-swizzled, x inline-cast) ----------------
__global__ __launch_bounds__(256) void prjgate_kernel(
    const bf16_t* __restrict__ att, const bf16_t* __restrict__ wot,
    const float* __restrict__ bo, const float* __restrict__ x,
    const bf16_t* __restrict__ wg1t, const bf16_t* __restrict__ wg2t,
    const float* __restrict__ bg, float* __restrict__ outp)
{
  __shared__ __align__(16) bf16_t prjT[16*256];
  const int wg = blockIdx.x;
  const int row0 = ((wg & 7)*80 + (wg >> 3)) * 16;
  const int tid = threadIdx.x;
  const int w = tid >> 6, lane = tid & 63, g = lane >> 4, l15 = lane & 15;
  const int arow = row0 + l15;

  {
    const bf16x8* Arow = (const bf16x8*)(att + (size_t)arow*DIM);
    bf16x8 afA[8];
    #pragma unroll
    for (int kc = 0; kc < 8; ++kc) afA[kc] = Arow[kc*4 + g];
    #pragma unroll
    for (int ct = 0; ct < 4; ++ct) {
      const int n = w*64 + ct*16 + l15;
      const bf16x8* Brow = (const bf16x8*)(wot + (size_t)n*DIM);
      f32x4 acc = {0.f,0.f,0.f,0.f};
      #pragma unroll
      for (int kc = 0; kc < 8; ++kc)
        acc = __builtin_amdgcn_mfma_f32_16x16x32_bf16(afA[kc], Brow[kc*4+g], acc, 0, 0, 0);
      const float bvo = bo[n];
      #pragma unroll
      for (int r = 0; r < 4; ++r)
        prjT[swz256(g*4 + r, n)] = (bf16_t)(acc[r] + bvo);
    }
  }
  __syncthreads();

  const float4* A1r = (const float4*)(x + (size_t)arow*DIM);
  bf16x8 a1[8], a2[8];
  #pragma unroll
  for (int kc = 0; kc < 8; ++kc) {
    const float4 f0 = A1r[kc*8 + g*2], f1 = A1r[kc*8 + g*2 + 1];
    bf16x8 v;
    v[0]=(bf16_t)f0.x; v[1]=(bf16_t)f0.y; v[2]=(bf16_t)f0.z; v[3]=(bf16_t)f0.w;
    v[4]=(bf16_t)f1.x; v[5]=(bf16_t)f1.y; v[6]=(bf16_t)f1.z; v[7]=(bf16_t)f1.w;
    a1[kc] = v;
    a2[kc] = *(const bf16x8*)&prjT[swz256(l15, kc*32 + g*8)];
  }
  #pragma unroll
  for (int ct = 0; ct < 4; ++ct) {
    const int n = w*64 + ct*16 + l15;
    const bf16x8* b1 = (const bf16x8*)(wg1t + (size_t)n*DIM);
    const bf16x8* b2 = (const bf16x8*)(wg2t + (size_t)n*DIM);
    f32x4 acc = {0.f,0.f,0.f,0.f};
    #pragma unroll
    for (int kc = 0; kc < 8; ++kc)
      acc = __builtin_amdgcn_mfma_f32_16x16x32_bf16(a1[kc], b1[kc*4+g], acc, 0, 0, 0);
    #pragma unroll
    for (int kc = 0; kc < 8; ++kc)
      acc = __builtin_amdgcn_mfma_f32_16x16x32_bf16(a2[kc], b2[kc*4+g], acc, 0, 0, 0);
    const float bgv = bg[n];
    #pragma unroll
    for (int r = 0; r < 4; ++r) {
      const int grow = row0 + g*4 + r;
      const float gate = 1.f / (1.f + __expf(-(acc[r] + bgv)));
      const float pv = (float)prjT[swz256(g*4 + r, n)];
      const float xv = x[(size_t)grow*DIM + n];
      outp[(size_t)grow*DIM + n] = gate*pv + (1.f - gate)*xv;
    }
  }
}

extern "C" void kernel_launch(void* const* d_in, const int* in_sizes, int n_in,
                              void* d_out, int out_size, void* d_ws, size_t ws_size,
                              hipStream_t stream)
{
  const float* x   = (const float*)d_in[0];
  const float* Wq  = (const float*)d_in[1];
  const float* bq  = (const float*)d_in[2];
  const float* Wk  = (const float*)d_in[3];
  const float* bk  = (const float*)d_in[4];
  const float* Wv  = (const float*)d_in[5];
  const float* bv  = (const float*)d_in[6];
  const float* Wp1 = (const float*)d_in[7];
  const float* bp1 = (const float*)d_in[8];
  const float* Wp2 = (const float*)d_in[9];
  const float* bp2 = (const float*)d_in[10];
  const float* Ws1 = (const float*)d_in[11];
  const float* bs1 = (const float*)d_in[12];
  const float* Ws2 = (const float*)d_in[13];
  const float* bs2 = (const float*)d_in[14];
  const float* Wo  = (const float*)d_in[15];
  const float* bo  = (const float*)d_in[16];
  const float* Wg  = (const float*)d_in[17];
  const float* bg  = (const float*)d_in[18];

  char* ws = (char*)d_ws;
  size_t off = 0;
  auto alloc = [&](size_t bytes) {
    char* p = ws + off;
    off += (bytes + 255) & ~(size_t)255;
    return p;
  };
  bf16_t* qbuf  = (bf16_t*)alloc((size_t)M_TOTAL*DIM*2);
  bf16_t* kbuf  = (bf16_t*)alloc((size_t)M_TOTAL*DIM*2);
  bf16_t* vbuf  = (bf16_t*)alloc((size_t)M_TOTAL*DIM*2);
  bf16_t* att   = (bf16_t*)alloc((size_t)M_TOTAL*DIM*2);
  bf16_t* btall = (bf16_t*)alloc((size_t)800*256*2);
  bf16_t* wot   = (bf16_t*)alloc(65536*2);
  bf16_t* wg1t  = (bf16_t*)alloc(65536*2);
  bf16_t* wg2t  = (bf16_t*)alloc(65536*2);
  float*  bias_all = (float*)alloc(832*4);
  bf16_t* sbb   = (bf16_t*)alloc((size_t)M_TOTAL*8*2);
  float*  posT  = (float*)alloc((size_t)HEADS*NPOS*4);
  (void)ws_size; (void)in_sizes; (void)n_in; (void)out_size;

  prep_all_kernel<<<NPREP, 256, 0, stream>>>(Ws1, bq, bk, bv, bs1,
                                             Wq, Wk, Wv, Wo, Wg, Wp1, bp1, Wp2, bp2,
                                             btall, bias_all, wot, wg1t, wg2t, posT);
  qkv_kernel<<<2080, 256, 0, stream>>>(x, btall, bias_all, Ws2, bs2,
                                       qbuf, kbuf, vbuf, sbb);
  attn_kernel<<<SEQ/64*HEADS*BL, 256, 0, stream>>>(qbuf, kbuf, vbuf, sbb, posT, att);
  prjgate_kernel<<<640, 256, 0, stream>>>(att, wot, bo, x, wg1t, wg2t, bg,
                                          (float*)d_out);
}

// Round 20
// 146.750 us; speedup vs baseline: 1.0582x; 1.0582x over previous
//
#include <hip/hip_runtime.h>

typedef __bf16 bf16_t;
typedef __bf16 bf16x4 __attribute__((ext_vector_type(4)));
typedef __bf16 bf16x8 __attribute__((ext_vector_type(8)));
typedef float  f32x4  __attribute__((ext_vector_type(4)));

#define HEADS 8
#define HEAD_DIM 32
#define DIM 256
#define BL 10
#define SEQ 1024
#define M_TOTAL (BL*SEQ)
#define QK_SCALE 0.17677669529663687f   // 1/sqrt(32)
#define LOG2E 1.4426950408889634f
#define SQRT_LOG2E 1.2011224087864498f
#define NPOS (63*63)

#define NCAST 2596
#define NTRANS 96
#define NPREP (NCAST + NTRANS + 16)

__device__ __forceinline__ int swz_idx(int row, int col) {
  return row*64 + (col ^ ((row & 7) << 3));
}
__device__ __forceinline__ int swz256(int row, int col) {
  return row*256 + (col ^ ((row & 7) << 3));
}

// ---------------- merged prep: cast | weight transpose | pos table ----------------
__global__ __launch_bounds__(256) void prep_all_kernel(
    const float* __restrict__ x, const float* __restrict__ Ws1,
    const float* __restrict__ bq, const float* __restrict__ bk,
    const float* __restrict__ bv, const float* __restrict__ bs1,
    const float* __restrict__ Wq, const float* __restrict__ Wk, const float* __restrict__ Wv,
    const float* __restrict__ Wo, const float* __restrict__ Wg,
    const float* __restrict__ Wp1, const float* __restrict__ bp1,
    const float* __restrict__ Wp2, const float* __restrict__ bp2,
    bf16_t* __restrict__ xb, bf16_t* __restrict__ btall, float* __restrict__ bias_all,
    bf16_t* __restrict__ wot, bf16_t* __restrict__ wg1t, bf16_t* __restrict__ wg2t,
    float* __restrict__ posT)
{
  __shared__ float tile[64][65];
  const int bid = blockIdx.x;
  const int tid = threadIdx.x;

  if (bid < NCAST) {
    const int NX4 = M_TOTAL*DIM/4;
    const int i = bid*256 + tid;
    if (i < NX4) {
      const float4 v = ((const float4*)x)[i];
      bf16x4 o; o[0]=(bf16_t)v.x; o[1]=(bf16_t)v.y; o[2]=(bf16_t)v.z; o[3]=(bf16_t)v.w;
      *(bf16x4*)(xb + (size_t)i*4) = o;
      return;
    }
    int idx = i - NX4;
    if (idx < 8192) {
      const int m = idx >> 8, k = idx & 255;
      btall[(768 + m)*256 + k] = (bf16_t)Ws1[k*32 + m];
      return;
    }
    idx -= 8192;
    if (idx < 832) {
      bias_all[idx] = (idx < 256) ? bq[idx] : (idx < 512) ? bk[idx-256] :
                      (idx < 768) ? bv[idx-512] : (idx < 800) ? bs1[idx-768] : 0.f;
    }
    return;
  }

  if (bid < NCAST + NTRANS) {
    const int t0 = bid - NCAST;
    const int z = t0 >> 4, bi = (t0 & 15) >> 2, bj = t0 & 3;
    const float* src; bf16_t* dst;
    switch (z) {
      case 0: src = Wq;          dst = btall;          break;
      case 1: src = Wk;          dst = btall + 65536;  break;
      case 2: src = Wv;          dst = btall + 131072; break;
      case 3: src = Wo;          dst = wot;            break;
      case 4: src = Wg;          dst = wg1t;           break;
      default: src = Wg + 65536; dst = wg2t;           break;
    }
    const int tr = tid >> 4, tc = tid & 15;
    #pragma unroll
    for (int i = 0; i < 4; ++i) {
      const float4 v = *(const float4*)(src + (size_t)(bi*64 + tr + 16*i)*256 + bj*64 + tc*4);
      float* tp = &tile[tr + 16*i][tc*4];
      tp[0]=v.x; tp[1]=v.y; tp[2]=v.z; tp[3]=v.w;
    }
    __syncthreads();
    #pragma unroll
    for (int i = 0; i < 4; ++i) {
      bf16x4 o;
      #pragma unroll
      for (int e = 0; e < 4; ++e) o[e] = (bf16_t)tile[tc*4 + e][tr + 16*i];
      *(bf16x4*)(dst + (size_t)(bj*64 + tr + 16*i)*256 + bi*64 + tc*4) = o;
    }
    return;
  }

  // ---- pos table (x LOG2E) ----
  {
    float* sm = &tile[0][0];
    float* w1 = sm; float* b1 = sm + 96; float* w2 = sm + 128; float* b2 = sm + 384;
    if (tid < 96) w1[tid] = Wp1[tid];
    if (tid < 32) b1[tid] = bp1[tid];
    w2[tid] = Wp2[tid];
    if (tid < 8)  b2[tid] = bp2[tid];
    __syncthreads();
    const int p = (bid - NCAST - NTRANS)*256 + tid;
    if (p >= NPOS) return;
    const float dy = (float)(p / 63 - 31);
    const float dx = (float)(p % 63 - 31);
    const float dist = sqrtf(dy*dy + dx*dx);
    float o[8];
    #pragma unroll
    for (int t = 0; t < 8; ++t) o[t] = b2[t];
    #pragma unroll
    for (int m = 0; m < 32; ++m) {
      float hv = fmaf(dy, w1[m], fmaf(dx, w1[32+m], fmaf(dist, w1[64+m], b1[m])));
      hv = fmaxf(hv, 0.f);
      #pragma unroll
      for (int t = 0; t < 8; ++t) o[t] = fmaf(hv, w2[m*8+t], o[t]);
    }
    #pragma unroll
    for (int t = 0; t < 8; ++t) posT[t*NPOS + p] = o[t]*LOG2E;
  }
}

// ---------------- fused QKV + hidden + s projection (XCD-swizzled grid) ----------------
__global__ __launch_bounds__(256) void qkv_kernel(
    const bf16_t* __restrict__ xb, const bf16_t* __restrict__ btall,
    const float* __restrict__ bias_all, const float* __restrict__ Ws2,
    const float* __restrict__ bs2,
    bf16_t* __restrict__ qbuf, bf16_t* __restrict__ kbuf, bf16_t* __restrict__ vbuf,
    bf16_t* __restrict__ sbb)
{
  __shared__ float hidlds[64][33];
  const int wg = blockIdx.x;
  const int xcd = wg & 7, within = wg >> 3;      // within 0..259
  const int mt = xcd*20 + within/13;
  const int ngb = within - (within/13)*13;
  const int tid = threadIdx.x;
  const int w = tid >> 6, lane = tid & 63, g = lane >> 4, l15 = lane & 15;
  const int arow = mt*64 + w*16 + l15;
  const bf16x8* Arow = (const bf16x8*)(xb + (size_t)arow*DIM);
  bf16x8 af[8];
  #pragma unroll
  for (int kc = 0; kc < 8; ++kc) af[kc] = Arow[kc*4 + g];
  if (ngb < 12) {
    bf16_t* dst = (ngb < 4) ? qbuf : (ngb < 8) ? kbuf : vbuf;
    const int coloff = (ngb & 3) * 64;
    const float scale = (ngb < 4) ? QK_SCALE*LOG2E : 1.f;
    for (int c = 0; c < 4; ++c) {
      const int n = ngb*64 + c*16 + l15;
      const bf16x8* Brow = (const bf16x8*)(btall + (size_t)n*DIM);
      f32x4 acc = {0.f,0.f,0.f,0.f};
      #pragma unroll
      for (int kc = 0; kc < 8; ++kc)
        acc = __builtin_amdgcn_mfma_f32_16x16x32_bf16(af[kc], Brow[kc*4+g], acc, 0, 0, 0);
      const float bvv = bias_all[n];
      #pragma unroll
      for (int r = 0; r < 4; ++r) {
        const int row = mt*64 + w*16 + g*4 + r;
        dst[(size_t)row*DIM + coloff + c*16 + l15] = (bf16_t)((acc[r] + bvv)*scale);
      }
    }
  } else {
    for (int c = 0; c < 2; ++c) {
      const int n = 768 + c*16 + l15;
      const bf16x8* Brow = (const bf16x8*)(btall + (size_t)n*DIM);
      f32x4 acc = {0.f,0.f,0.f,0.f};
      #pragma unroll
      for (int kc = 0; kc < 8; ++kc)
        acc = __builtin_amdgcn_mfma_f32_16x16x32_bf16(af[kc], Brow[kc*4+g], acc, 0, 0, 0);
      const float bvv = bias_all[n];
      #pragma unroll
      for (int r = 0; r < 4; ++r)
        hidlds[w*16 + g*4 + r][c*16 + l15] = fmaxf(acc[r] + bvv, 0.f);
    }
    __syncthreads();
    if (tid < 64) {
      float sv[8];
      #pragma unroll
      for (int t = 0; t < 8; ++t) sv[t] = bs2[t];
      #pragma unroll
      for (int m = 0; m < 32; ++m) {
        const float hv = hidlds[tid][m];
        #pragma unroll
        for (int t = 0; t < 8; ++t) sv[t] = fmaf(hv, Ws2[m*8+t], sv[t]);
      }
      bf16x8 o;
      #pragma unroll
      for (int t = 0; t < 8; ++t) o[t] = (bf16_t)(sv[t]*SQRT_LOG2E);
      *(bf16x8*)(sbb + (size_t)(mt*64 + tid)*8) = o;
    }
  }
}

// ---------------- flash attention (r14 body): swapped QK^T, dbuf K/V, ----
// ---------------- lane-local softmax + in-register row-sum ----------------
__global__ __launch_bounds__(256) void attn_kernel(
    const bf16_t* __restrict__ qb, const bf16_t* __restrict__ kb,
    const bf16_t* __restrict__ vb, const bf16_t* __restrict__ sbb,
    const float* __restrict__ posT, bf16_t* __restrict__ att)
{
  __shared__ __align__(16) bf16_t lk[2][64*64];   // cols 0-31 K, 32-39 s, 40-63 zero
  __shared__ __align__(16) bf16_t lv[2][32*64];   // rows 0-31 V^T
  __shared__ __align__(16) bf16_t lp[64*64];      // P[q][j], wave-local rows
  __shared__ float ptab[33*63];

  const int wg = blockIdx.x;
  const int xcd = wg & 7, within = wg >> 3;
  const int pair = xcd*10 + (within >> 4);
  const int it = within & 15;
  const int h = pair & 7, b = pair >> 3;
  const int i0 = it*64, iy0 = it*2;
  const int tid = threadIdx.x;
  const int w = tid >> 6, lane = tid & 63, g = lane >> 4, l15 = lane & 15;
  const int r4 = tid >> 2, q4 = tid & 3;

  // ---- stage pos slice ----
  for (int p = tid; p < 33*63; p += 256) {
    const int rr = p / 63, cc = p - rr*63;
    ptab[p] = posT[h*NPOS + (iy0 + rr)*63 + cc];
  }
  // ---- one-time: lk zero cols 40..63 in both buffers ----
  for (int p = tid; p < 384; p += 256) {
    const int bufi = p / 192, rem = p - bufi*192;
    const int rr = rem / 3, ch = 5 + (rem % 3);
    bf16x8 z = {};
    *(bf16x8*)&lk[bufi][swz_idx(rr, ch*8)] = z;
  }

  // ---- Q fragments ----
  const int qrow = b*SEQ + i0 + w*16 + l15;
  const bf16x8 aq0 = *(const bf16x8*)(qb + (size_t)qrow*DIM + h*HEAD_DIM + g*8);
  bf16x8 aq1 = {};
  if (g == 0) aq1 = *(const bf16x8*)(sbb + (size_t)qrow*8);

  const int iq = i0 + w*16 + l15;
  const int rbase_i = (iq >> 5) - iy0 + 31;   // {31,32}
  const int ixr = iq & 31;

  // ---- tile 0 into regs, write buf0 ----
  bf16x8 kreg = *(const bf16x8*)(kb + (size_t)(b*SEQ + r4)*DIM + h*HEAD_DIM + q4*8);
  bf16x8 vreg = *(const bf16x8*)(vb + (size_t)(b*SEQ + r4)*DIM + h*HEAD_DIM + q4*8);
  bf16x8 sreg = {};
  if (tid < 64) sreg = *(const bf16x8*)(sbb + (size_t)(b*SEQ + tid)*8);
  *(bf16x8*)&lk[0][swz_idx(r4, q4*8)] = kreg;
  #pragma unroll
  for (int e = 0; e < 8; ++e) {
    const int d = q4*8 + e;
    lv[0][d*64 + (r4 ^ ((d & 7) << 3))] = vreg[e];
  }
  if (tid < 64) *(bf16x8*)&lk[0][swz_idx(tid, 32)] = sreg;
  __syncthreads();

  f32x4 accO0 = {0.f,0.f,0.f,0.f}, accO1 = {0.f,0.f,0.f,0.f};
  float mrow = -1e30f, lrow = 0.f;

  for (int jt = 0; jt < 16; ++jt) {
    const int pb = jt & 1;
    // ---- prefetch next tile into regs (overlaps with compute) ----
    if (jt < 15) {
      const int grow = b*SEQ + jt*64 + 64;
      kreg = *(const bf16x8*)(kb + (size_t)(grow + r4)*DIM + h*HEAD_DIM + q4*8);
      vreg = *(const bf16x8*)(vb + (size_t)(grow + r4)*DIM + h*HEAD_DIM + q4*8);
      if (tid < 64) sreg = *(const bf16x8*)(sbb + (size_t)(grow + tid)*8);
    }

    // ---- QK^T swapped: K as A, Q as B  ->  D[j][q] ----
    f32x4 s4[4];
    #pragma unroll
    for (int c = 0; c < 4; ++c) {
      const bf16x8 kf0 = *(const bf16x8*)&lk[pb][swz_idx(c*16 + l15, g*8)];
      const bf16x8 kf1 = *(const bf16x8*)&lk[pb][swz_idx(c*16 + l15, 32 + g*8)];
      f32x4 acc = {0.f,0.f,0.f,0.f};
      acc = __builtin_amdgcn_mfma_f32_16x16x32_bf16(kf0, aq0, acc, 0, 0, 0);
      acc = __builtin_amdgcn_mfma_f32_16x16x32_bf16(kf1, aq1, acc, 0, 0, 0);
      s4[c] = acc;
    }

    // ---- + pos (i fixed per thread, j varies) ----
    #pragma unroll
    for (int c = 0; c < 4; ++c) {
      #pragma unroll
      for (int r = 0; r < 4; ++r) {
        const int jl = c*16 + g*4 + r;
        const int jy = jt*2 + (jl >> 5);
        const int jx = jl & 31;
        s4[c][r] += ptab[(rbase_i - jy)*63 + (ixr - jx + 31)];
      }
    }

    // ---- softmax over j for fixed q: lane-local max + 2 shfl ----
    float m16 = s4[0][0];
    #pragma unroll
    for (int c = 0; c < 4; ++c) {
      #pragma unroll
      for (int r = 0; r < 4; ++r) m16 = fmaxf(m16, s4[c][r]);
    }
    m16 = fmaxf(m16, __shfl_xor(m16, 16));
    m16 = fmaxf(m16, __shfl_xor(m16, 32));
    if (__any(m16 > mrow + 8.f)) {
      const float mn = fmaxf(mrow, m16);
      const float alpha = exp2f(mrow - mn);
      mrow = mn;
      lrow *= alpha;
      #pragma unroll
      for (int r = 0; r < 4; ++r) {
        const float aO = __shfl(alpha, g*16 + g*4 + r);   // alpha of q = w*16+g*4+r
        accO0[r] *= aO; accO1[r] *= aO;
      }
    }
    float rsum = 0.f;
    #pragma unroll
    for (int c = 0; c < 4; ++c) {
      #pragma unroll
      for (int r = 0; r < 4; ++r) {
        s4[c][r] = exp2f(s4[c][r] - mrow);
        rsum += s4[c][r];
      }
    }
    lrow += rsum;

    // ---- P -> LDS (wave-local rows, b64 runs) ----
    #pragma unroll
    for (int c = 0; c < 4; ++c) {
      bf16x4 o;
      #pragma unroll
      for (int r = 0; r < 4; ++r) o[r] = (bf16_t)s4[c][r];
      *(bf16x4*)&lp[swz_idx(w*16 + l15, c*16 + g*4)] = o;
    }

    // ---- PV ----
    const int prow = w*16 + l15;
    #pragma unroll
    for (int kc = 0; kc < 2; ++kc) {
      const bf16x8 ap  = *(const bf16x8*)&lp[swz_idx(prow, kc*32 + g*8)];
      const bf16x8 bv0 = *(const bf16x8*)&lv[pb][swz_idx(l15,      kc*32 + g*8)];
      const bf16x8 bv1 = *(const bf16x8*)&lv[pb][swz_idx(16 + l15, kc*32 + g*8)];
      accO0 = __builtin_amdgcn_mfma_f32_16x16x32_bf16(ap, bv0, accO0, 0, 0, 0);
      accO1 = __builtin_amdgcn_mfma_f32_16x16x32_bf16(ap, bv1, accO1, 0, 0, 0);
    }

    // ---- write staged regs -> buf pb^1 ----
    if (jt < 15) {
      *(bf16x8*)&lk[pb^1][swz_idx(r4, q4*8)] = kreg;
      #pragma unroll
      for (int e = 0; e < 8; ++e) {
        const int d = q4*8 + e;
        lv[pb^1][d*64 + (r4 ^ ((d & 7) << 3))] = vreg[e];
      }
      if (tid < 64) *(bf16x8*)&lk[pb^1][swz_idx(tid, 32)] = sreg;
    }
    __syncthreads();
  }

  // ---- epilogue: reduce lrow across g-lanes, broadcast per output row ----
  lrow += __shfl_xor(lrow, 16);
  lrow += __shfl_xor(lrow, 32);
  #pragma unroll
  for (int r = 0; r < 4; ++r) {
    const int row = b*SEQ + i0 + w*16 + g*4 + r;
    const float inv = 1.f / __shfl(lrow, g*16 + g*4 + r);
    att[(size_t)row*DIM + h*HEAD_DIM + l15]      = (bf16_t)(accO0[r]*inv);
    att[(size_t)row*DIM + h*HEAD_DIM + 16 + l15] = (bf16_t)(accO1[r]*inv);
  }
}

// ---------------- fused Wo-projection + gate (XCD-swizzled grid) ----------------
__global__ __launch_bounds__(256) void prjgate_kernel(
    const bf16_t* __restrict__ att, const bf16_t* __restrict__ wot,
    const float* __restrict__ bo, const bf16_t* __restrict__ xb,
    const float* __restrict__ x, const bf16_t* __restrict__ wg1t,
    const bf16_t* __restrict__ wg2t, const float* __restrict__ bg,
    float* __restrict__ outp)
{
  __shared__ __align__(16) bf16_t prjT[16*256];
  const int wg = blockIdx.x;
  const int row0 = ((wg & 7)*80 + (wg >> 3)) * 16;
  const int tid = threadIdx.x;
  const int w = tid >> 6, lane = tid & 63, g = lane >> 4, l15 = lane & 15;
  const int arow = row0 + l15;

  {
    const bf16x8* Arow = (const bf16x8*)(att + (size_t)arow*DIM);
    bf16x8 afA[8];
    #pragma unroll
    for (int kc = 0; kc < 8; ++kc) afA[kc] = Arow[kc*4 + g];
    #pragma unroll
    for (int ct = 0; ct < 4; ++ct) {
      const int n = w*64 + ct*16 + l15;
      const bf16x8* Brow = (const bf16x8*)(wot + (size_t)n*DIM);
      f32x4 acc = {0.f,0.f,0.f,0.f};
      #pragma unroll
      for (int kc = 0; kc < 8; ++kc)
        acc = __builtin_amdgcn_mfma_f32_16x16x32_bf16(afA[kc], Brow[kc*4+g], acc, 0, 0, 0);
      const float bvo = bo[n];
      #pragma unroll
      for (int r = 0; r < 4; ++r)
        prjT[swz256(g*4 + r, n)] = (bf16_t)(acc[r] + bvo);
    }
  }
  __syncthreads();

  const bf16x8* A1r = (const bf16x8*)(xb + (size_t)arow*DIM);
  bf16x8 a1[8], a2[8];
  #pragma unroll
  for (int kc = 0; kc < 8; ++kc) {
    a1[kc] = A1r[kc*4 + g];
    a2[kc] = *(const bf16x8*)&prjT[swz256(l15, kc*32 + g*8)];
  }
  #pragma unroll
  for (int ct = 0; ct < 4; ++ct) {
    const int n = w*64 + ct*16 + l15;
    const bf16x8* b1 = (const bf16x8*)(wg1t + (size_t)n*DIM);
    const bf16x8* b2 = (const bf16x8*)(wg2t + (size_t)n*DIM);
    f32x4 acc = {0.f,0.f,0.f,0.f};
    #pragma unroll
    for (int kc = 0; kc < 8; ++kc)
      acc = __builtin_amdgcn_mfma_f32_16x16x32_bf16(a1[kc], b1[kc*4+g], acc, 0, 0, 0);
    #pragma unroll
    for (int kc = 0; kc < 8; ++kc)
      acc = __builtin_amdgcn_mfma_f32_16x16x32_bf16(a2[kc], b2[kc*4+g], acc, 0, 0, 0);
    const float bgv = bg[n];
    #pragma unroll
    for (int r = 0; r < 4; ++r) {
      const int grow = row0 + g*4 + r;
      const float gate = 1.f / (1.f + __expf(-(acc[r] + bgv)));
      const float pv = (float)prjT[swz256(g*4 + r, n)];
      const float xv = x[(size_t)grow*DIM + n];
      outp[(size_t)grow*DIM + n] = gate*pv + (1.f - gate)*xv;
    }
  }
}

extern "C" void kernel_launch(void* const* d_in, const int* in_sizes, int n_in,
                              void* d_out, int out_size, void* d_ws, size_t ws_size,
                              hipStream_t stream)
{
  const float* x   = (const float*)d_in[0];
  const float* Wq  = (const float*)d_in[1];
  const float* bq  = (const float*)d_in[2];
  const float* Wk  = (const float*)d_in[3];
  const float* bk  = (const float*)d_in[4];
  const float* Wv  = (const float*)d_in[5];
  const float* bv  = (const float*)d_in[6];
  const float* Wp1 = (const float*)d_in[7];
  const float* bp1 = (const float*)d_in[8];
  const float* Wp2 = (const float*)d_in[9];
  const float* bp2 = (const float*)d_in[10];
  const float* Ws1 = (const float*)d_in[11];
  const float* bs1 = (const float*)d_in[12];
  const float* Ws2 = (const float*)d_in[13];
  const float* bs2 = (const float*)d_in[14];
  const float* Wo  = (const float*)d_in[15];
  const float* bo  = (const float*)d_in[16];
  const float* Wg  = (const float*)d_in[17];
  const float* bg  = (const float*)d_in[18];

  char* ws = (char*)d_ws;
  size_t off = 0;
  auto alloc = [&](size_t bytes) {
    char* p = ws + off;
    off += (bytes + 255) & ~(size_t)255;
    return p;
  };
  bf16_t* xb    = (bf16_t*)alloc((size_t)M_TOTAL*DIM*2);
  bf16_t* qbuf  = (bf16_t*)alloc((size_t)M_TOTAL*DIM*2);
  bf16_t* kbuf  = (bf16_t*)alloc((size_t)M_TOTAL*DIM*2);
  bf16_t* vbuf  = (bf16_t*)alloc((size_t)M_TOTAL*DIM*2);
  bf16_t* att   = (bf16_t*)alloc((size_t)M_TOTAL*DIM*2);
  bf16_t* btall = (bf16_t*)alloc((size_t)800*256*2);
  bf16_t* wot   = (bf16_t*)alloc(65536*2);
  bf16_t* wg1t  = (bf16_t*)alloc(65536*2);
  bf16_t* wg2t  = (bf16_t*)alloc(65536*2);
  float*  bias_all = (float*)alloc(832*4);
  bf16_t* sbb   = (bf16_t*)alloc((size_t)M_TOTAL*8*2);
  float*  posT  = (float*)alloc((size_t)HEADS*NPOS*4);
  (void)ws_size; (void)in_sizes; (void)n_in; (void)out_size;

  prep_all_kernel<<<NPREP, 256, 0, stream>>>(x, Ws1, bq, bk, bv, bs1,
                                             Wq, Wk, Wv, Wo, Wg, Wp1, bp1, Wp2, bp2,
                                             xb, btall, bias_all, wot, wg1t, wg2t, posT);
  qkv_kernel<<<2080, 256, 0, stream>>>(xb, btall, bias_all, Ws2, bs2,
                                       qbuf, kbuf, vbuf, sbb);
  attn_kernel<<<SEQ/64*HEADS*BL, 256, 0, stream>>>(qbuf, kbuf, vbuf, sbb, posT, att);
  prjgate_kernel<<<640, 256, 0, stream>>>(att, wot, bo, xb, x, wg1t, wg2t, bg,
                                          (float*)d_out);
}